// Round 3
// baseline (606.933 us; speedup 1.0000x reference)
//
#include <hip/hip_runtime.h>
#include <hip/hip_bf16.h>
#include <stdint.h>

#define NE 8
#define T_TOK 4096
#define H_DIM 1024
#define I_DIM 4096
#define CAP 4096
#define BM 128
#define BN 128
#define BK 64
#define KSPLIT 2

typedef __attribute__((ext_vector_type(8))) short bf16x8;
typedef __attribute__((ext_vector_type(4))) float f32x4;
typedef __attribute__((ext_vector_type(8))) unsigned short u16x8;

__device__ __forceinline__ unsigned short f2bf(float f) {
  __hip_bfloat16 h = __float2bfloat16(f);
  return *reinterpret_cast<unsigned short*>(&h);
}

__device__ __forceinline__ void lds_load16(const void* g, void* l) {
  __builtin_amdgcn_global_load_lds((__attribute__((address_space(1))) void*)g,
                                   (__attribute__((address_space(3))) void*)l,
                                   16, 0, 0);
}

// bijective XCD swizzle (nwg % 8 == 0): hw bid -> logical id such that each
// XCD owns a contiguous logical chunk (consecutive logicals share B-panels)
__device__ __forceinline__ int xcd_swz(int bid, int nwg) {
  return (bid & 7) * (nwg >> 3) + (bid >> 3);
}

// ---------------- router: 1 wave per token ----------------
__global__ void router_kernel(const float* __restrict__ x,
                              const float* __restrict__ rw,
                              int* __restrict__ counts,
                              int* __restrict__ perm,
                              float* __restrict__ pw) {
  const int t = blockIdx.x;
  const int lane = threadIdx.x;  // 64 threads
  float acc[NE];
#pragma unroll
  for (int e = 0; e < NE; ++e) acc[e] = 0.f;
  const float* xr = x + (size_t)t * H_DIM;
#pragma unroll
  for (int it = 0; it < H_DIM / 64; ++it) {
    int d = it * 64 + lane;
    float xv = xr[d];
#pragma unroll
    for (int e = 0; e < NE; ++e) acc[e] += xv * rw[e * H_DIM + d];
  }
#pragma unroll
  for (int e = 0; e < NE; ++e) {
#pragma unroll
    for (int off = 32; off > 0; off >>= 1) acc[e] += __shfl_xor(acc[e], off);
  }
  if (lane == 0) {
    int i0 = 0;
#pragma unroll
    for (int e = 1; e < NE; ++e)
      if (acc[e] > acc[i0]) i0 = e;
    int i1 = (i0 == 0) ? 1 : 0;
#pragma unroll
    for (int e = 0; e < NE; ++e)
      if (e != i0 && acc[e] > acc[i1]) i1 = e;
    float la = acc[i0], lb = acc[i1];
    float r = expf(lb - la);          // <= 1
    float wa = 1.f / (1.f + r);       // normalized top-2 softmax weights
    float wb = 1.f - wa;
    int p0 = atomicAdd(&counts[i0], 1);
    perm[i0 * CAP + p0] = t;
    pw[i0 * CAP + p0] = wa;
    int p1 = atomicAdd(&counts[i1], 1);
    perm[i1 * CAP + p1] = t;
    pw[i1 * CAP + p1] = wb;
  }
}

// ---------------- x -> bf16 ----------------
__global__ void convert_x_kernel(const float* __restrict__ x,
                                 unsigned short* __restrict__ xb) {
  int i = blockIdx.x * blockDim.x + threadIdx.x;  // one float4 each
  float4 v = reinterpret_cast<const float4*>(x)[i];
  ushort4 o;
  o.x = f2bf(v.x); o.y = f2bf(v.y); o.z = f2bf(v.z); o.w = f2bf(v.w);
  reinterpret_cast<ushort4*>(xb)[i] = o;
}

// ---------------- transpose + convert: src [E][R][C] f32 -> dst [E][C][R] bf16
// 64x64 tiles, float4 global loads, ushort8 global stores (16B/lane both ways)
__global__ void __launch_bounds__(256) transpose_conv_kernel(
    const float* __restrict__ src, unsigned short* __restrict__ dst,
    int R, int C) {
  __shared__ float tile[64][65];
  const int e = blockIdx.z;
  const int c0 = blockIdx.x * 64, r0 = blockIdx.y * 64;
  const float* s = src + (size_t)e * R * C;
  unsigned short* d = dst + (size_t)e * R * C;
  const int tid = threadIdx.x;
  const int lr = tid >> 4, lc = (tid & 15) << 2;
#pragma unroll
  for (int j = 0; j < 4; ++j) {
    float4 v = *reinterpret_cast<const float4*>(
        &s[(size_t)(r0 + j * 16 + lr) * C + c0 + lc]);
    tile[j * 16 + lr][lc + 0] = v.x;
    tile[j * 16 + lr][lc + 1] = v.y;
    tile[j * 16 + lr][lc + 2] = v.z;
    tile[j * 16 + lr][lc + 3] = v.w;
  }
  __syncthreads();
  const int oc = tid >> 3, orr = (tid & 7) << 3;
#pragma unroll
  for (int j = 0; j < 2; ++j) {
    int c = j * 32 + oc;
    u16x8 o;
#pragma unroll
    for (int k = 0; k < 8; ++k) o[k] = f2bf(tile[orr + k][c]);
    *reinterpret_cast<u16x8*>(&d[(size_t)(c0 + c) * R + r0 + orr]) = o;
  }
}

// ---------------- FFN1: inter = gelu(X[perm] @ w_in + b_in), bf16 out --------
// single-buffered 2-barrier loop; grid NE*32*32 (XCD-swizzled), 256 threads
__global__ void __launch_bounds__(256) ffn1_kernel(
    const unsigned short* __restrict__ xb,
    const unsigned short* __restrict__ win_t,  // [E][I][H]
    const float* __restrict__ b_in,            // [E][I]
    const int* __restrict__ counts,
    const int* __restrict__ perm,
    unsigned short* __restrict__ inter) {
  const int logical = xcd_swz(blockIdx.x, NE * 32 * 32);
  const int e = logical >> 10;
  const int nb = (logical >> 5) & 31;
  const int mb = logical & 31;
  const int cnt = counts[e];
  if (mb * BM >= cnt) return;
  int poff = 0;
  for (int i = 0; i < e; ++i) poff += (counts[i] + BM - 1) & ~(BM - 1);

  __shared__ unsigned short Asm[BM][BK];
  __shared__ unsigned short Bsm[BN][BK];
  __shared__ int s_tok[BM];

  const int tid = threadIdx.x;
  if (tid < BM) {
    int idx = mb * BM + tid;
    s_tok[tid] = perm[e * CAP + min(idx, cnt - 1)];
  }

  const int wave = tid >> 6, lane = tid & 63;
  const int wr = wave >> 1, wc = wave & 1;
  const int l16 = lane & 15, l4 = lane >> 4;
  const unsigned short* Bbase = win_t + (size_t)e * I_DIM * H_DIM;

  f32x4 acc[4][4] = {};

  for (int kt = 0; kt < H_DIM / BK; ++kt) {
    __syncthreads();
#pragma unroll
    for (int it = 0; it < 4; ++it) {
      int id = it * 256 + tid;
      int r = id >> 3, kc = id & 7;
      const unsigned short* ga =
          xb + (size_t)s_tok[r] * H_DIM + kt * BK + kc * 8;
      lds_load16(ga, (char*)&Asm[0][0] + id * 16);
      const unsigned short* gb =
          Bbase + (size_t)(nb * BN + r) * H_DIM + kt * BK + kc * 8;
      lds_load16(gb, (char*)&Bsm[0][0] + id * 16);
    }
    __syncthreads();
#pragma unroll
    for (int kk = 0; kk < 2; ++kk) {
      bf16x8 af[4], bfr[4];
#pragma unroll
      for (int m = 0; m < 4; ++m)
        af[m] = *(const bf16x8*)&Asm[wr * 64 + m * 16 + l16][kk * 32 + l4 * 8];
#pragma unroll
      for (int n = 0; n < 4; ++n)
        bfr[n] = *(const bf16x8*)&Bsm[wc * 64 + n * 16 + l16][kk * 32 + l4 * 8];
#pragma unroll
      for (int m = 0; m < 4; ++m)
#pragma unroll
        for (int n = 0; n < 4; ++n)
          acc[m][n] =
              __builtin_amdgcn_mfma_f32_16x16x32_bf16(af[m], bfr[n], acc[m][n], 0, 0, 0);
    }
  }

  const size_t rowbase = (size_t)poff + mb * BM;
#pragma unroll
  for (int n = 0; n < 4; ++n) {
    int col = nb * BN + wc * 64 + n * 16 + l16;
    float bias = b_in[e * I_DIM + col];
#pragma unroll
    for (int m = 0; m < 4; ++m) {
#pragma unroll
      for (int j = 0; j < 4; ++j) {
        int r = wr * 64 + m * 16 + l4 * 4 + j;
        float v = acc[m][n][j] + bias;
        // tanh-form GELU: v * sigmoid(1.59577(v + 0.044715 v^3)); |err| <~1e-3
        float t = __expf(-1.5957691216057308f * v - 0.07135481627f * v * v * v);
        float g = v / (1.f + t);
        inter[(rowbase + r) * (size_t)I_DIM + col] = f2bf(g);
      }
    }
  }
}

// ---------------- FFN2: out[tok] += w * (inter @ w_out + b_out) --------------
// single-buffered 2-barrier loop + split-K=2 (partials merged via fp32 atomics)
// grid: NE * KSPLIT * 8(nb) * 32(mb) (XCD-swizzled), 256 threads; LDS 33 KB
__global__ void __launch_bounds__(256) ffn2_kernel(
    const unsigned short* __restrict__ inter,
    const unsigned short* __restrict__ wout_t,  // [E][H][I]
    const float* __restrict__ b_out,            // [E][H]
    const int* __restrict__ counts,
    const int* __restrict__ perm,
    const float* __restrict__ pw,
    float* __restrict__ out) {
  const int logical = xcd_swz(blockIdx.x, NE * KSPLIT * 8 * 32);
  const int e = logical >> 9;
  const int ks = (logical >> 8) & (KSPLIT - 1);
  const int nb = (logical >> 5) & 7;
  const int mb = logical & 31;
  const int cnt = counts[e];
  if (mb * BM >= cnt) return;
  int poff = 0;
  for (int i = 0; i < e; ++i) poff += (counts[i] + BM - 1) & ~(BM - 1);

  __shared__ unsigned short Asm[BM][BK];
  __shared__ unsigned short Bsm[BN][BK];
  __shared__ int s_tok[BM];
  __shared__ float s_wt[BM];

  const int tid = threadIdx.x;
  if (tid < BM) {
    int idx = mb * BM + tid;
    int ci = min(idx, cnt - 1);
    s_tok[tid] = perm[e * CAP + ci];
    s_wt[tid] = pw[e * CAP + ci];
  }

  const int wave = tid >> 6, lane = tid & 63;
  const int wr = wave >> 1, wc = wave & 1;
  const int l16 = lane & 15, l4 = lane >> 4;
  const unsigned short* Bbase = wout_t + (size_t)e * H_DIM * I_DIM;
  const size_t rowbase = (size_t)poff + mb * BM;

  f32x4 acc[4][4] = {};

  const int NKS = (I_DIM / BK) / KSPLIT;  // 32 K-steps per split
  for (int kt = ks * NKS; kt < (ks + 1) * NKS; ++kt) {
    __syncthreads();
#pragma unroll
    for (int it = 0; it < 4; ++it) {
      int id = it * 256 + tid;
      int r = id >> 3, kc = id & 7;
      lds_load16(inter + (rowbase + r) * (size_t)I_DIM + kt * BK + kc * 8,
                 (char*)&Asm[0][0] + id * 16);
      lds_load16(Bbase + (size_t)(nb * BN + r) * I_DIM + kt * BK + kc * 8,
                 (char*)&Bsm[0][0] + id * 16);
    }
    __syncthreads();
#pragma unroll
    for (int kk = 0; kk < 2; ++kk) {
      bf16x8 af[4], bfr[4];
#pragma unroll
      for (int m = 0; m < 4; ++m)
        af[m] = *(const bf16x8*)&Asm[wr * 64 + m * 16 + l16][kk * 32 + l4 * 8];
#pragma unroll
      for (int n = 0; n < 4; ++n)
        bfr[n] = *(const bf16x8*)&Bsm[wc * 64 + n * 16 + l16][kk * 32 + l4 * 8];
#pragma unroll
      for (int m = 0; m < 4; ++m)
#pragma unroll
        for (int n = 0; n < 4; ++n)
          acc[m][n] =
              __builtin_amdgcn_mfma_f32_16x16x32_bf16(af[m], bfr[n], acc[m][n], 0, 0, 0);
    }
  }

#pragma unroll
  for (int n = 0; n < 4; ++n) {
    int col = nb * BN + wc * 64 + n * 16 + l16;
    float bias = (ks == 0) ? b_out[e * H_DIM + col] : 0.f;
#pragma unroll
    for (int m = 0; m < 4; ++m) {
#pragma unroll
      for (int j = 0; j < 4; ++j) {
        int r = wr * 64 + m * 16 + l4 * 4 + j;
        if (mb * BM + r < cnt) {
          atomicAdd(&out[(size_t)s_tok[r] * H_DIM + col],
                    s_wt[r] * (acc[m][n][j] + bias));
        }
      }
    }
  }
}

extern "C" void kernel_launch(void* const* d_in, const int* in_sizes, int n_in,
                              void* d_out, int out_size, void* d_ws, size_t ws_size,
                              hipStream_t stream) {
  const float* x     = (const float*)d_in[0];
  const float* rw    = (const float*)d_in[1];
  const float* w_in  = (const float*)d_in[2];
  const float* b_in  = (const float*)d_in[3];
  const float* w_out = (const float*)d_in[4];
  const float* b_out = (const float*)d_in[5];
  float* out = (float*)d_out;

  char* ws = (char*)d_ws;
  size_t off = 0;
  auto alloc = [&](size_t bytes) {
    char* p = ws + off;
    off = (off + bytes + 255) & ~(size_t)255;
    return p;
  };
  int* counts            = (int*)alloc(NE * 4);
  int* perm              = (int*)alloc((size_t)NE * CAP * 4);
  float* pw              = (float*)alloc((size_t)NE * CAP * 4);
  unsigned short* xb     = (unsigned short*)alloc((size_t)T_TOK * H_DIM * 2);
  unsigned short* win_t  = (unsigned short*)alloc((size_t)NE * H_DIM * I_DIM * 2);
  unsigned short* wout_t = (unsigned short*)alloc((size_t)NE * H_DIM * I_DIM * 2);
  unsigned short* inter  = (unsigned short*)alloc((size_t)(T_TOK * 2 + NE * BM) * I_DIM * 2);
  if (off > ws_size) return;  // ws too small -> visible correctness failure

  hipMemsetAsync(d_out, 0, (size_t)out_size * sizeof(float), stream);
  hipMemsetAsync(counts, 0, NE * sizeof(int), stream);

  router_kernel<<<T_TOK, 64, 0, stream>>>(x, rw, counts, perm, pw);
  convert_x_kernel<<<(T_TOK * H_DIM / 4) / 256, 256, 0, stream>>>(x, xb);
  transpose_conv_kernel<<<dim3(I_DIM / 64, H_DIM / 64, NE), 256, 0, stream>>>(
      w_in, win_t, H_DIM, I_DIM);
  transpose_conv_kernel<<<dim3(H_DIM / 64, I_DIM / 64, NE), 256, 0, stream>>>(
      w_out, wout_t, I_DIM, H_DIM);
  ffn1_kernel<<<NE * 32 * 32, 256, 0, stream>>>(xb, win_t, b_in, counts, perm, inter);
  ffn2_kernel<<<NE * KSPLIT * 8 * 32, 256, 0, stream>>>(inter, wout_t, b_out,
                                                        counts, perm, pw, out);
}

// Round 4
// 541.807 us; speedup vs baseline: 1.1202x; 1.1202x over previous
//
#include <hip/hip_runtime.h>
#include <hip/hip_bf16.h>
#include <stdint.h>

#define NE 8
#define T_TOK 4096
#define H_DIM 1024
#define I_DIM 4096
#define CAP 4096

typedef __attribute__((ext_vector_type(8))) short bf16x8;
typedef __attribute__((ext_vector_type(4))) float f32x4;
typedef __attribute__((ext_vector_type(8))) unsigned short u16x8;

__device__ __forceinline__ unsigned short f2bf(float f) {
  __hip_bfloat16 h = __float2bfloat16(f);
  return *reinterpret_cast<unsigned short*>(&h);
}

__device__ __forceinline__ void lds_load16(const void* g, void* l) {
  __builtin_amdgcn_global_load_lds((__attribute__((address_space(1))) void*)g,
                                   (__attribute__((address_space(3))) void*)l,
                                   16, 0, 0);
}

// bijective XCD swizzle (nwg % 8 == 0): each XCD owns a contiguous logical chunk
__device__ __forceinline__ int xcd_swz(int bid, int nwg) {
  return (bid & 7) * (nwg >> 3) + (bid >> 3);
}

// ---------------- router: 1 wave per token ----------------
// outputs: counts[e], perm[e][pos]=tok (ffn1 gather), se[2t+k]=(e<<20)|pos,
// wtok[2t+k]=combine weight
__global__ void router_kernel(const float* __restrict__ x,
                              const float* __restrict__ rw,
                              int* __restrict__ counts,
                              int* __restrict__ perm,
                              int* __restrict__ se,
                              float* __restrict__ wtok) {
  const int t = blockIdx.x;
  const int lane = threadIdx.x;  // 64 threads
  float acc[NE];
#pragma unroll
  for (int e = 0; e < NE; ++e) acc[e] = 0.f;
  const float* xr = x + (size_t)t * H_DIM;
#pragma unroll
  for (int it = 0; it < H_DIM / 64; ++it) {
    int d = it * 64 + lane;
    float xv = xr[d];
#pragma unroll
    for (int e = 0; e < NE; ++e) acc[e] += xv * rw[e * H_DIM + d];
  }
#pragma unroll
  for (int e = 0; e < NE; ++e) {
#pragma unroll
    for (int off = 32; off > 0; off >>= 1) acc[e] += __shfl_xor(acc[e], off);
  }
  if (lane == 0) {
    int i0 = 0;
#pragma unroll
    for (int e = 1; e < NE; ++e)
      if (acc[e] > acc[i0]) i0 = e;
    int i1 = (i0 == 0) ? 1 : 0;
#pragma unroll
    for (int e = 0; e < NE; ++e)
      if (e != i0 && acc[e] > acc[i1]) i1 = e;
    float la = acc[i0], lb = acc[i1];
    float r = expf(lb - la);          // <= 1
    float wa = 1.f / (1.f + r);       // normalized top-2 softmax weights
    float wb = 1.f - wa;
    int p0 = atomicAdd(&counts[i0], 1);
    perm[i0 * CAP + p0] = t;
    se[2 * t + 0] = (i0 << 20) | p0;
    wtok[2 * t + 0] = wa;
    int p1 = atomicAdd(&counts[i1], 1);
    perm[i1 * CAP + p1] = t;
    se[2 * t + 1] = (i1 << 20) | p1;
    wtok[2 * t + 1] = wb;
  }
}

// ---------------- x -> bf16 ----------------
__global__ void convert_x_kernel(const float* __restrict__ x,
                                 unsigned short* __restrict__ xb) {
  int i = blockIdx.x * blockDim.x + threadIdx.x;  // one float4 each
  float4 v = reinterpret_cast<const float4*>(x)[i];
  ushort4 o;
  o.x = f2bf(v.x); o.y = f2bf(v.y); o.z = f2bf(v.z); o.w = f2bf(v.w);
  reinterpret_cast<ushort4*>(xb)[i] = o;
}

// ---------------- transpose + convert: src [E][R][C] f32 -> dst [E][C][R] bf16
__global__ void __launch_bounds__(256) transpose_conv_kernel(
    const float* __restrict__ src, unsigned short* __restrict__ dst,
    int R, int C) {
  __shared__ float tile[64][65];
  const int e = blockIdx.z;
  const int c0 = blockIdx.x * 64, r0 = blockIdx.y * 64;
  const float* s = src + (size_t)e * R * C;
  unsigned short* d = dst + (size_t)e * R * C;
  const int tid = threadIdx.x;
  const int lr = tid >> 4, lc = (tid & 15) << 2;
#pragma unroll
  for (int j = 0; j < 4; ++j) {
    float4 v = *reinterpret_cast<const float4*>(
        &s[(size_t)(r0 + j * 16 + lr) * C + c0 + lc]);
    tile[j * 16 + lr][lc + 0] = v.x;
    tile[j * 16 + lr][lc + 1] = v.y;
    tile[j * 16 + lr][lc + 2] = v.z;
    tile[j * 16 + lr][lc + 3] = v.w;
  }
  __syncthreads();
  const int oc = tid >> 3, orr = (tid & 7) << 3;
#pragma unroll
  for (int j = 0; j < 2; ++j) {
    int c = j * 32 + oc;
    u16x8 o;
#pragma unroll
    for (int k = 0; k < 8; ++k) o[k] = f2bf(tile[orr + k][c]);
    *reinterpret_cast<u16x8*>(&d[(size_t)(c0 + c) * R + r0 + orr]) = o;
  }
}

// ---------------- FFN1: inter = gelu(X[perm] @ w_in + b_in), bf16 out --------
// 256x256 tile, BK=64, 512 thr (8 waves 2Mx4N), dbuf 1-barrier loop.
// LDS 128KB dynamic. grid 8e*16mb*16nb = 2048 (XCD-swizzled), early-exit.
__global__ void __launch_bounds__(512, 2) ffn1_kernel(
    const unsigned short* __restrict__ xb,
    const unsigned short* __restrict__ win_t,  // [E][I][H]
    const float* __restrict__ b_in,            // [E][I]
    const int* __restrict__ counts,
    const int* __restrict__ perm,
    unsigned short* __restrict__ inter) {
  const int logical = xcd_swz(blockIdx.x, NE * 16 * 16);
  const int e = logical >> 8;
  const int nb = (logical >> 4) & 15;
  const int mb = logical & 15;
  const int cnt = counts[e];
  if (mb * 256 >= cnt) return;
  int poff = 0;
  for (int i = 0; i < e; ++i) poff += (counts[i] + 255) & ~255;

  extern __shared__ char smem[];  // [2][ A 32KB | B 32KB ]

  const int tid = threadIdx.x;
  int tokr[4];
#pragma unroll
  for (int it = 0; it < 4; ++it) {
    int r = (it * 512 + tid) >> 3;
    tokr[it] = perm[e * CAP + min(mb * 256 + r, cnt - 1)];
  }

  const int wave = tid >> 6, lane = tid & 63;
  const int wr = wave >> 2, wn = wave & 3;  // 2M x 4N
  const int l16 = lane & 15, l4 = lane >> 4;
  const unsigned short* Bbase =
      win_t + (size_t)e * I_DIM * H_DIM + (size_t)(nb * 256) * H_DIM;

  auto stage = [&](int b, int kt) {
    char* Ab = smem + b * 65536;
    char* Bb = Ab + 32768;
#pragma unroll
    for (int it = 0; it < 4; ++it) {
      int id = it * 512 + tid;
      int kc = id & 7;
      lds_load16(xb + (size_t)tokr[it] * H_DIM + kt * 64 + kc * 8, Ab + id * 16);
      lds_load16(Bbase + (size_t)(id >> 3) * H_DIM + kt * 64 + kc * 8,
                 Bb + id * 16);
    }
  };

  f32x4 acc[8][4] = {};

  stage(0, 0);
  __syncthreads();  // implicit vmcnt(0): buf0 resident

  const int NK = H_DIM / 64;
  for (int kt = 0; kt < NK; ++kt) {
    const int cur = kt & 1;
    if (kt + 1 < NK) stage(cur ^ 1, kt + 1);  // prefetch overlaps compute
    const unsigned short(*Asm)[64] =
        reinterpret_cast<const unsigned short(*)[64]>(smem + cur * 65536);
    const unsigned short(*Bsm)[64] =
        reinterpret_cast<const unsigned short(*)[64]>(smem + cur * 65536 + 32768);
#pragma unroll
    for (int kk = 0; kk < 2; ++kk) {
      bf16x8 af[8], bf[4];
#pragma unroll
      for (int m = 0; m < 8; ++m)
        af[m] = *(const bf16x8*)&Asm[wr * 128 + m * 16 + l16][kk * 32 + l4 * 8];
#pragma unroll
      for (int n = 0; n < 4; ++n)
        bf[n] = *(const bf16x8*)&Bsm[wn * 64 + n * 16 + l16][kk * 32 + l4 * 8];
#pragma unroll
      for (int m = 0; m < 8; ++m)
#pragma unroll
        for (int n = 0; n < 4; ++n)
          acc[m][n] =
              __builtin_amdgcn_mfma_f32_16x16x32_bf16(af[m], bf[n], acc[m][n], 0, 0, 0);
    }
    __syncthreads();  // drains prefetch + guards buffer swap
  }

  const size_t rowbase = (size_t)poff + mb * 256;
#pragma unroll
  for (int n = 0; n < 4; ++n) {
    int col = nb * 256 + wn * 64 + n * 16 + l16;
    float bias = b_in[e * I_DIM + col];
#pragma unroll
    for (int m = 0; m < 8; ++m) {
#pragma unroll
      for (int j = 0; j < 4; ++j) {
        int r = wr * 128 + m * 16 + l4 * 4 + j;
        float v = acc[m][n][j] + bias;
        // tanh-form GELU: v * sigmoid(1.59577(v + 0.044715 v^3)); |err| <~1e-3
        float t = __expf(-1.5957691216057308f * v - 0.07135481627f * v * v * v);
        float g = v / (1.f + t);
        inter[(rowbase + r) * (size_t)I_DIM + col] = f2bf(g);
      }
    }
  }
}

// ---------------- FFN2: y[slot] = inter @ w_out + b_out (dense, no atomics) --
// 256x128 tile, BK=64, 512 thr (8 waves 4Mx2N), dbuf 1-barrier loop.
// LDS 96KB dynamic. grid 8e*16mb*8nb = 1024 (XCD-swizzled), early-exit.
__global__ void __launch_bounds__(512, 2) ffn2_kernel(
    const unsigned short* __restrict__ inter,
    const unsigned short* __restrict__ wout_t,  // [E][H][I]
    const float* __restrict__ b_out,            // [E][H]
    const int* __restrict__ counts,
    float* __restrict__ y) {                    // [slot][H]
  const int logical = xcd_swz(blockIdx.x, NE * 16 * 8);
  const int e = logical >> 7;
  const int nb = (logical >> 4) & 7;
  const int mb = logical & 15;
  const int cnt = counts[e];
  if (mb * 256 >= cnt) return;
  int poff = 0;
  for (int i = 0; i < e; ++i) poff += (counts[i] + 255) & ~255;

  extern __shared__ char smem[];  // [2][ A 32KB | B 16KB ]

  const int tid = threadIdx.x;
  const int wave = tid >> 6, lane = tid & 63;
  const int wrm = wave >> 1, wn2 = wave & 1;  // 4M x 2N
  const int l16 = lane & 15, l4 = lane >> 4;
  const unsigned short* Bbase =
      wout_t + (size_t)e * H_DIM * I_DIM + (size_t)(nb * 128) * I_DIM;
  const size_t rowbase = (size_t)poff + mb * 256;

  auto stage = [&](int b, int kt) {
    char* Ab = smem + b * 49152;
    char* Bb = Ab + 32768;
#pragma unroll
    for (int it = 0; it < 4; ++it) {
      int id = it * 512 + tid;
      int kc = id & 7;
      lds_load16(inter + (rowbase + (id >> 3)) * (size_t)I_DIM + kt * 64 + kc * 8,
                 Ab + id * 16);
    }
#pragma unroll
    for (int it = 0; it < 2; ++it) {
      int id = it * 512 + tid;
      int kc = id & 7;
      lds_load16(Bbase + (size_t)(id >> 3) * I_DIM + kt * 64 + kc * 8,
                 Bb + id * 16);
    }
  };

  f32x4 acc[4][4] = {};

  stage(0, 0);
  __syncthreads();

  const int NK = I_DIM / 64;
  for (int kt = 0; kt < NK; ++kt) {
    const int cur = kt & 1;
    if (kt + 1 < NK) stage(cur ^ 1, kt + 1);
    const unsigned short(*Asm)[64] =
        reinterpret_cast<const unsigned short(*)[64]>(smem + cur * 49152);
    const unsigned short(*Bsm)[64] =
        reinterpret_cast<const unsigned short(*)[64]>(smem + cur * 49152 + 32768);
#pragma unroll
    for (int kk = 0; kk < 2; ++kk) {
      bf16x8 af[4], bf[4];
#pragma unroll
      for (int m = 0; m < 4; ++m)
        af[m] = *(const bf16x8*)&Asm[wrm * 64 + m * 16 + l16][kk * 32 + l4 * 8];
#pragma unroll
      for (int n = 0; n < 4; ++n)
        bf[n] = *(const bf16x8*)&Bsm[wn2 * 64 + n * 16 + l16][kk * 32 + l4 * 8];
#pragma unroll
      for (int m = 0; m < 4; ++m)
#pragma unroll
        for (int n = 0; n < 4; ++n)
          acc[m][n] =
              __builtin_amdgcn_mfma_f32_16x16x32_bf16(af[m], bf[n], acc[m][n], 0, 0, 0);
    }
    __syncthreads();
  }

#pragma unroll
  for (int n = 0; n < 4; ++n) {
    int col = nb * 128 + wn2 * 64 + n * 16 + l16;
    float bias = b_out[e * H_DIM + col];
#pragma unroll
    for (int m = 0; m < 4; ++m) {
#pragma unroll
      for (int j = 0; j < 4; ++j) {
        int r = wrm * 64 + m * 16 + l4 * 4 + j;
        y[(rowbase + r) * (size_t)H_DIM + col] = acc[m][n][j] + bias;
      }
    }
  }
}

// ---------------- combine: out[t] = w0*y[slot0] + w1*y[slot1] ---------------
__global__ void __launch_bounds__(256) combine_kernel(
    const float* __restrict__ y, const int* __restrict__ counts,
    const int* __restrict__ se, const float* __restrict__ wtok,
    float* __restrict__ out) {
  const int t = blockIdx.x;
  int poff[NE];
  int run = 0;
#pragma unroll
  for (int e = 0; e < NE; ++e) {
    poff[e] = run;
    run += (counts[e] + 255) & ~255;
  }
  int c0 = se[2 * t], c1 = se[2 * t + 1];
  float w0 = wtok[2 * t], w1 = wtok[2 * t + 1];
  const float* y0 = y + (size_t)(poff[c0 >> 20] + (c0 & 0xFFFFF)) * H_DIM;
  const float* y1 = y + (size_t)(poff[c1 >> 20] + (c1 & 0xFFFFF)) * H_DIM;
  int h = threadIdx.x * 4;
  float4 a = *reinterpret_cast<const float4*>(y0 + h);
  float4 b = *reinterpret_cast<const float4*>(y1 + h);
  float4 o;
  o.x = w0 * a.x + w1 * b.x;
  o.y = w0 * a.y + w1 * b.y;
  o.z = w0 * a.z + w1 * b.z;
  o.w = w0 * a.w + w1 * b.w;
  *reinterpret_cast<float4*>(out + (size_t)t * H_DIM + h) = o;
}

extern "C" void kernel_launch(void* const* d_in, const int* in_sizes, int n_in,
                              void* d_out, int out_size, void* d_ws, size_t ws_size,
                              hipStream_t stream) {
  const float* x     = (const float*)d_in[0];
  const float* rw    = (const float*)d_in[1];
  const float* w_in  = (const float*)d_in[2];
  const float* b_in  = (const float*)d_in[3];
  const float* w_out = (const float*)d_in[4];
  const float* b_out = (const float*)d_in[5];
  float* out = (float*)d_out;

  char* ws = (char*)d_ws;
  size_t off = 0;
  auto alloc = [&](size_t bytes) {
    char* p = ws + off;
    off = (off + bytes + 255) & ~(size_t)255;
    return p;
  };
  int* counts            = (int*)alloc(NE * 4);
  int* perm              = (int*)alloc((size_t)NE * CAP * 4);
  int* se                = (int*)alloc((size_t)T_TOK * 2 * 4);
  float* wtok            = (float*)alloc((size_t)T_TOK * 2 * 4);
  unsigned short* xb     = (unsigned short*)alloc((size_t)T_TOK * H_DIM * 2);
  unsigned short* win_t  = (unsigned short*)alloc((size_t)NE * H_DIM * I_DIM * 2);
  unsigned short* wout_t = (unsigned short*)alloc((size_t)NE * H_DIM * I_DIM * 2);
  unsigned short* inter  = (unsigned short*)alloc((size_t)(T_TOK * 2 + NE * 256) * I_DIM * 2);
  // y overlays the dead xb+win_t region (both dead before ffn2 writes y):
  // need 10240*1024*4 = 42MB <= 8.4MB + 64MB
  float* y = (float*)xb;
  if (off > ws_size) return;  // ws too small -> visible correctness failure

  hipMemsetAsync(counts, 0, NE * sizeof(int), stream);

  static bool attr_done = false;
  if (!attr_done) {
    hipFuncSetAttribute((const void*)ffn1_kernel,
                        hipFuncAttributeMaxDynamicSharedMemorySize, 131072);
    hipFuncSetAttribute((const void*)ffn2_kernel,
                        hipFuncAttributeMaxDynamicSharedMemorySize, 98304);
    attr_done = true;
  }

  router_kernel<<<T_TOK, 64, 0, stream>>>(x, rw, counts, perm, se, wtok);
  convert_x_kernel<<<(T_TOK * H_DIM / 4) / 256, 256, 0, stream>>>(x, xb);
  transpose_conv_kernel<<<dim3(I_DIM / 64, H_DIM / 64, NE), 256, 0, stream>>>(
      w_in, win_t, H_DIM, I_DIM);
  transpose_conv_kernel<<<dim3(H_DIM / 64, I_DIM / 64, NE), 256, 0, stream>>>(
      w_out, wout_t, I_DIM, H_DIM);
  ffn1_kernel<<<NE * 16 * 16, 512, 131072, stream>>>(xb, win_t, b_in, counts,
                                                     perm, inter);
  ffn2_kernel<<<NE * 16 * 8, 512, 98304, stream>>>(inter, wout_t, b_out, counts, y);
  combine_kernel<<<T_TOK, 256, 0, stream>>>(y, counts, se, wtok, out);
}

// Round 5
// 489.483 us; speedup vs baseline: 1.2399x; 1.1069x over previous
//
#include <hip/hip_runtime.h>
#include <hip/hip_bf16.h>
#include <stdint.h>

#define NE 8
#define T_TOK 4096
#define H_DIM 1024
#define I_DIM 4096
#define CAP 4096

typedef __attribute__((ext_vector_type(8))) short bf16x8;
typedef __attribute__((ext_vector_type(4))) float f32x4;
typedef __attribute__((ext_vector_type(8))) unsigned short u16x8;

#define VMCNT8 asm volatile("s_waitcnt vmcnt(8)" ::: "memory")
#define VMCNT6 asm volatile("s_waitcnt vmcnt(6)" ::: "memory")
#define VMCNT0 asm volatile("s_waitcnt vmcnt(0)" ::: "memory")
#define CFENCE asm volatile("" ::: "memory")

__device__ __forceinline__ unsigned short f2bf(float f) {
  __hip_bfloat16 h = __float2bfloat16(f);
  return *reinterpret_cast<unsigned short*>(&h);
}

__device__ __forceinline__ void lds_load16(const void* g, void* l) {
  __builtin_amdgcn_global_load_lds((__attribute__((address_space(1))) void*)g,
                                   (__attribute__((address_space(3))) void*)l,
                                   16, 0, 0);
}

// swizzled LDS fragment read: tile layout [rows][64 bf16] (128B rows, 8x16B
// chunks); content chunk cc of row lives at physical chunk cc ^ (row&7)
__device__ __forceinline__ const bf16x8* lds_frag(const char* base, int row,
                                                  int cc) {
  return (const bf16x8*)(base + row * 128 + ((cc ^ (row & 7)) << 4));
}

// bijective XCD swizzle (nwg % 8 == 0): each XCD owns a contiguous logical chunk
__device__ __forceinline__ int xcd_swz(int bid, int nwg) {
  return (bid & 7) * (nwg >> 3) + (bid >> 3);
}

// ---------------- router: 1 wave per token ----------------
__global__ void router_kernel(const float* __restrict__ x,
                              const float* __restrict__ rw,
                              int* __restrict__ counts,
                              int* __restrict__ perm,
                              int* __restrict__ se,
                              float* __restrict__ wtok) {
  const int t = blockIdx.x;
  const int lane = threadIdx.x;  // 64 threads
  float acc[NE];
#pragma unroll
  for (int e = 0; e < NE; ++e) acc[e] = 0.f;
  const float* xr = x + (size_t)t * H_DIM;
#pragma unroll
  for (int it = 0; it < H_DIM / 64; ++it) {
    int d = it * 64 + lane;
    float xv = xr[d];
#pragma unroll
    for (int e = 0; e < NE; ++e) acc[e] += xv * rw[e * H_DIM + d];
  }
#pragma unroll
  for (int e = 0; e < NE; ++e) {
#pragma unroll
    for (int off = 32; off > 0; off >>= 1) acc[e] += __shfl_xor(acc[e], off);
  }
  if (lane == 0) {
    int i0 = 0;
#pragma unroll
    for (int e = 1; e < NE; ++e)
      if (acc[e] > acc[i0]) i0 = e;
    int i1 = (i0 == 0) ? 1 : 0;
#pragma unroll
    for (int e = 0; e < NE; ++e)
      if (e != i0 && acc[e] > acc[i1]) i1 = e;
    float la = acc[i0], lb = acc[i1];
    float r = expf(lb - la);          // <= 1
    float wa = 1.f / (1.f + r);       // normalized top-2 softmax weights
    float wb = 1.f - wa;
    int p0 = atomicAdd(&counts[i0], 1);
    perm[i0 * CAP + p0] = t;
    se[2 * t + 0] = (i0 << 20) | p0;
    wtok[2 * t + 0] = wa;
    int p1 = atomicAdd(&counts[i1], 1);
    perm[i1 * CAP + p1] = t;
    se[2 * t + 1] = (i1 << 20) | p1;
    wtok[2 * t + 1] = wb;
  }
}

// ---------------- x -> bf16 ----------------
__global__ void convert_x_kernel(const float* __restrict__ x,
                                 unsigned short* __restrict__ xb) {
  int i = blockIdx.x * blockDim.x + threadIdx.x;  // one float4 each
  float4 v = reinterpret_cast<const float4*>(x)[i];
  ushort4 o;
  o.x = f2bf(v.x); o.y = f2bf(v.y); o.z = f2bf(v.z); o.w = f2bf(v.w);
  reinterpret_cast<ushort4*>(xb)[i] = o;
}

// ---------------- transpose + convert: src [E][R][C] f32 -> dst [E][C][R] bf16
__global__ void __launch_bounds__(256) transpose_conv_kernel(
    const float* __restrict__ src, unsigned short* __restrict__ dst,
    int R, int C) {
  __shared__ float tile[64][65];
  const int e = blockIdx.z;
  const int c0 = blockIdx.x * 64, r0 = blockIdx.y * 64;
  const float* s = src + (size_t)e * R * C;
  unsigned short* d = dst + (size_t)e * R * C;
  const int tid = threadIdx.x;
  const int lr = tid >> 4, lc = (tid & 15) << 2;
#pragma unroll
  for (int j = 0; j < 4; ++j) {
    float4 v = *reinterpret_cast<const float4*>(
        &s[(size_t)(r0 + j * 16 + lr) * C + c0 + lc]);
    tile[j * 16 + lr][lc + 0] = v.x;
    tile[j * 16 + lr][lc + 1] = v.y;
    tile[j * 16 + lr][lc + 2] = v.z;
    tile[j * 16 + lr][lc + 3] = v.w;
  }
  __syncthreads();
  const int oc = tid >> 3, orr = (tid & 7) << 3;
#pragma unroll
  for (int j = 0; j < 2; ++j) {
    int c = j * 32 + oc;
    u16x8 o;
#pragma unroll
    for (int k = 0; k < 8; ++k) o[k] = f2bf(tile[orr + k][c]);
    *reinterpret_cast<u16x8*>(&d[(size_t)(c0 + c) * R + r0 + orr]) = o;
  }
}

// ---------------- FFN1: inter = gelu(X[perm] @ w_in + b_in), bf16 out --------
// 256x256 tile, BK=64, 512 thr (8 waves 2Mx4N). Deep pipeline: 2 LDS buffers,
// counted vmcnt (loads span raw barriers, T4), T2 chunk-swizzle, T5 setprio.
// LDS 128KB dynamic. grid 8e*16mb*16nb = 2048 (XCD-swizzled), early-exit.
__global__ void __launch_bounds__(512, 2) ffn1_kernel(
    const unsigned short* __restrict__ xb,
    const unsigned short* __restrict__ win_t,  // [E][I][H]
    const float* __restrict__ b_in,            // [E][I]
    const int* __restrict__ counts,
    const int* __restrict__ perm,
    unsigned short* __restrict__ inter) {
  const int logical = xcd_swz(blockIdx.x, NE * 16 * 16);
  const int e = logical >> 8;
  const int nb = (logical >> 4) & 15;
  const int mb = logical & 15;
  const int cnt = counts[e];
  if (mb * 256 >= cnt) return;
  int poff = 0;
  for (int i = 0; i < e; ++i) poff += (counts[i] + 255) & ~255;

  extern __shared__ char smem[];  // [2][ A 32KB | B 32KB ]

  const int tid = threadIdx.x;
  int tokr[4];
#pragma unroll
  for (int it = 0; it < 4; ++it) {
    int r = (it * 512 + tid) >> 3;
    tokr[it] = perm[e * CAP + min(mb * 256 + r, cnt - 1)];
  }

  const int wave = tid >> 6, lane = tid & 63;
  const int wr = wave >> 2, wn = wave & 3;  // 2M x 4N
  const int l16 = lane & 15, l4 = lane >> 4;
  const unsigned short* Bbase =
      win_t + (size_t)e * I_DIM * H_DIM + (size_t)(nb * 256) * H_DIM;

  // stage tile kt into buffer b: 8 gload_lds/thread, source chunk pre-swizzled
  auto stage = [&](int b, int kt) {
#pragma unroll
    for (int it = 0; it < 4; ++it) {
      int id = it * 512 + tid;
      int r = id >> 3;
      int cs = (id & 7) ^ (r & 7);  // involution: LDS content is swizzled
      lds_load16(xb + (size_t)tokr[it] * H_DIM + kt * 64 + cs * 8,
                 smem + b * 65536 + id * 16);
      lds_load16(Bbase + (size_t)r * H_DIM + kt * 64 + cs * 8,
                 smem + b * 65536 + 32768 + id * 16);
    }
  };

  f32x4 acc[8][4] = {};

  stage(0, 0);
  stage(1, 1);

  const int NK = H_DIM / 64;  // 16
  for (int kt = 0; kt < NK; ++kt) {
    const int cur = kt & 1;
    // counted wait: tile kt's 8 loads retired, tile kt+1's stay in flight
    if (kt < NK - 1) { VMCNT8; } else { VMCNT0; }
    __builtin_amdgcn_s_barrier();
    CFENCE;
    const char* Ab = smem + cur * 65536;
    const char* Bb = Ab + 32768;
#pragma unroll
    for (int kk = 0; kk < 2; ++kk) {
      bf16x8 af[8], bv[4];
#pragma unroll
      for (int m = 0; m < 8; ++m)
        af[m] = *lds_frag(Ab, wr * 128 + m * 16 + l16, kk * 4 + l4);
#pragma unroll
      for (int n = 0; n < 4; ++n)
        bv[n] = *lds_frag(Bb, wn * 64 + n * 16 + l16, kk * 4 + l4);
      __builtin_amdgcn_s_setprio(1);
#pragma unroll
      for (int m = 0; m < 8; ++m)
#pragma unroll
        for (int n = 0; n < 4; ++n)
          acc[m][n] =
              __builtin_amdgcn_mfma_f32_16x16x32_bf16(af[m], bv[n], acc[m][n], 0, 0, 0);
      __builtin_amdgcn_s_setprio(0);
    }
    CFENCE;
    __builtin_amdgcn_s_barrier();  // all waves done reading buf[cur]
    CFENCE;
    if (kt + 2 < NK) stage(cur, kt + 2);
  }

  const size_t rowbase = (size_t)poff + mb * 256;
#pragma unroll
  for (int n = 0; n < 4; ++n) {
    int col = nb * 256 + wn * 64 + n * 16 + l16;
    float bias = b_in[e * I_DIM + col];
#pragma unroll
    for (int m = 0; m < 8; ++m) {
#pragma unroll
      for (int j = 0; j < 4; ++j) {
        int r = wr * 128 + m * 16 + l4 * 4 + j;
        float v = acc[m][n][j] + bias;
        // tanh-form GELU: v * sigmoid(1.59577(v + 0.044715 v^3)); |err| <~1e-3
        float t = __expf(-1.5957691216057308f * v - 0.07135481627f * v * v * v);
        float g = v / (1.f + t);
        inter[(rowbase + r) * (size_t)I_DIM + col] = f2bf(g);
      }
    }
  }
}

// ---------------- FFN2: y[slot] = inter @ w_out + b_out (dense, no atomics) --
// 256x128 tile, BK=64, 512 thr (8 waves 4Mx2N). Same deep pipeline (6 loads ->
// vmcnt(6)). LDS 96KB dynamic. grid 8e*16mb*8nb = 1024 (XCD-swizzled).
__global__ void __launch_bounds__(512, 2) ffn2_kernel(
    const unsigned short* __restrict__ inter,
    const unsigned short* __restrict__ wout_t,  // [E][H][I]
    const float* __restrict__ b_out,            // [E][H]
    const int* __restrict__ counts,
    float* __restrict__ y) {                    // [slot][H]
  const int logical = xcd_swz(blockIdx.x, NE * 16 * 8);
  const int e = logical >> 7;
  const int nb = (logical >> 4) & 7;
  const int mb = logical & 15;
  const int cnt = counts[e];
  if (mb * 256 >= cnt) return;
  int poff = 0;
  for (int i = 0; i < e; ++i) poff += (counts[i] + 255) & ~255;

  extern __shared__ char smem[];  // [2][ A 32KB | B 16KB ]

  const int tid = threadIdx.x;
  const int wave = tid >> 6, lane = tid & 63;
  const int wrm = wave >> 1, wn2 = wave & 1;  // 4M x 2N
  const int l16 = lane & 15, l4 = lane >> 4;
  const unsigned short* Bbase =
      wout_t + (size_t)e * H_DIM * I_DIM + (size_t)(nb * 128) * I_DIM;
  const size_t rowbase = (size_t)poff + mb * 256;

  auto stage = [&](int b, int kt) {
#pragma unroll
    for (int it = 0; it < 4; ++it) {
      int id = it * 512 + tid;
      int r = id >> 3;
      int cs = (id & 7) ^ (r & 7);
      lds_load16(inter + (rowbase + r) * (size_t)I_DIM + kt * 64 + cs * 8,
                 smem + b * 49152 + id * 16);
    }
#pragma unroll
    for (int it = 0; it < 2; ++it) {
      int id = it * 512 + tid;
      int r = id >> 3;
      int cs = (id & 7) ^ (r & 7);
      lds_load16(Bbase + (size_t)r * I_DIM + kt * 64 + cs * 8,
                 smem + b * 49152 + 32768 + id * 16);
    }
  };

  f32x4 acc[4][4] = {};

  stage(0, 0);
  stage(1, 1);

  const int NK = I_DIM / 64;  // 64
  for (int kt = 0; kt < NK; ++kt) {
    const int cur = kt & 1;
    if (kt < NK - 1) { VMCNT6; } else { VMCNT0; }
    __builtin_amdgcn_s_barrier();
    CFENCE;
    const char* Ab = smem + cur * 49152;
    const char* Bb = Ab + 32768;
#pragma unroll
    for (int kk = 0; kk < 2; ++kk) {
      bf16x8 af[4], bv[4];
#pragma unroll
      for (int m = 0; m < 4; ++m)
        af[m] = *lds_frag(Ab, wrm * 64 + m * 16 + l16, kk * 4 + l4);
#pragma unroll
      for (int n = 0; n < 4; ++n)
        bv[n] = *lds_frag(Bb, wn2 * 64 + n * 16 + l16, kk * 4 + l4);
      __builtin_amdgcn_s_setprio(1);
#pragma unroll
      for (int m = 0; m < 4; ++m)
#pragma unroll
        for (int n = 0; n < 4; ++n)
          acc[m][n] =
              __builtin_amdgcn_mfma_f32_16x16x32_bf16(af[m], bv[n], acc[m][n], 0, 0, 0);
      __builtin_amdgcn_s_setprio(0);
    }
    CFENCE;
    __builtin_amdgcn_s_barrier();
    CFENCE;
    if (kt + 2 < NK) stage(cur, kt + 2);
  }

#pragma unroll
  for (int n = 0; n < 4; ++n) {
    int col = nb * 128 + wn2 * 64 + n * 16 + l16;
    float bias = b_out[e * H_DIM + col];
#pragma unroll
    for (int m = 0; m < 4; ++m) {
#pragma unroll
      for (int j = 0; j < 4; ++j) {
        int r = wrm * 64 + m * 16 + l4 * 4 + j;
        y[(rowbase + r) * (size_t)H_DIM + col] = acc[m][n][j] + bias;
      }
    }
  }
}

// ---------------- combine: out[t] = w0*y[slot0] + w1*y[slot1] ---------------
__global__ void __launch_bounds__(256) combine_kernel(
    const float* __restrict__ y, const int* __restrict__ counts,
    const int* __restrict__ se, const float* __restrict__ wtok,
    float* __restrict__ out) {
  const int t = blockIdx.x;
  int poff[NE];
  int run = 0;
#pragma unroll
  for (int e = 0; e < NE; ++e) {
    poff[e] = run;
    run += (counts[e] + 255) & ~255;
  }
  int c0 = se[2 * t], c1 = se[2 * t + 1];
  float w0 = wtok[2 * t], w1 = wtok[2 * t + 1];
  const float* y0 = y + (size_t)(poff[c0 >> 20] + (c0 & 0xFFFFF)) * H_DIM;
  const float* y1 = y + (size_t)(poff[c1 >> 20] + (c1 & 0xFFFFF)) * H_DIM;
  int h = threadIdx.x * 4;
  float4 a = *reinterpret_cast<const float4*>(y0 + h);
  float4 b = *reinterpret_cast<const float4*>(y1 + h);
  float4 o;
  o.x = w0 * a.x + w1 * b.x;
  o.y = w0 * a.y + w1 * b.y;
  o.z = w0 * a.z + w1 * b.z;
  o.w = w0 * a.w + w1 * b.w;
  *reinterpret_cast<float4*>(out + (size_t)t * H_DIM + h) = o;
}

extern "C" void kernel_launch(void* const* d_in, const int* in_sizes, int n_in,
                              void* d_out, int out_size, void* d_ws, size_t ws_size,
                              hipStream_t stream) {
  const float* x     = (const float*)d_in[0];
  const float* rw    = (const float*)d_in[1];
  const float* w_in  = (const float*)d_in[2];
  const float* b_in  = (const float*)d_in[3];
  const float* w_out = (const float*)d_in[4];
  const float* b_out = (const float*)d_in[5];
  float* out = (float*)d_out;

  char* ws = (char*)d_ws;
  size_t off = 0;
  auto alloc = [&](size_t bytes) {
    char* p = ws + off;
    off = (off + bytes + 255) & ~(size_t)255;
    return p;
  };
  int* counts            = (int*)alloc(NE * 4);
  int* perm              = (int*)alloc((size_t)NE * CAP * 4);
  int* se                = (int*)alloc((size_t)T_TOK * 2 * 4);
  float* wtok            = (float*)alloc((size_t)T_TOK * 2 * 4);
  unsigned short* xb     = (unsigned short*)alloc((size_t)T_TOK * H_DIM * 2);
  unsigned short* win_t  = (unsigned short*)alloc((size_t)NE * H_DIM * I_DIM * 2);
  unsigned short* wout_t = (unsigned short*)alloc((size_t)NE * H_DIM * I_DIM * 2);
  unsigned short* inter  = (unsigned short*)alloc((size_t)(T_TOK * 2 + NE * 256) * I_DIM * 2);
  // y overlays the dead xb+win_t region (both dead before ffn2 writes y):
  // need 10240*1024*4 = 42MB <= 8.4MB + 64MB
  float* y = (float*)xb;
  if (off > ws_size) return;  // ws too small -> visible correctness failure

  hipMemsetAsync(counts, 0, NE * sizeof(int), stream);

  static bool attr_done = false;
  if (!attr_done) {
    hipFuncSetAttribute((const void*)ffn1_kernel,
                        hipFuncAttributeMaxDynamicSharedMemorySize, 131072);
    hipFuncSetAttribute((const void*)ffn2_kernel,
                        hipFuncAttributeMaxDynamicSharedMemorySize, 98304);
    attr_done = true;
  }

  router_kernel<<<T_TOK, 64, 0, stream>>>(x, rw, counts, perm, se, wtok);
  convert_x_kernel<<<(T_TOK * H_DIM / 4) / 256, 256, 0, stream>>>(x, xb);
  transpose_conv_kernel<<<dim3(I_DIM / 64, H_DIM / 64, NE), 256, 0, stream>>>(
      w_in, win_t, H_DIM, I_DIM);
  transpose_conv_kernel<<<dim3(H_DIM / 64, I_DIM / 64, NE), 256, 0, stream>>>(
      w_out, wout_t, I_DIM, H_DIM);
  ffn1_kernel<<<NE * 16 * 16, 512, 131072, stream>>>(xb, win_t, b_in, counts,
                                                     perm, inter);
  ffn2_kernel<<<NE * 16 * 8, 512, 98304, stream>>>(inter, wout_t, b_out, counts, y);
  combine_kernel<<<T_TOK, 256, 0, stream>>>(y, counts, se, wtok, out);
}

// Round 6
// 441.673 us; speedup vs baseline: 1.3742x; 1.1082x over previous
//
#include <hip/hip_runtime.h>
#include <hip/hip_bf16.h>
#include <stdint.h>

#define NE 8
#define T_TOK 4096
#define H_DIM 1024
#define I_DIM 4096
#define CAP 4096
#define RBMAX 40  // max total 256-row blocks: 8192/256 + 8 = 40

typedef __attribute__((ext_vector_type(8))) short bf16x8;
typedef __attribute__((ext_vector_type(4))) float f32x4;
typedef __attribute__((ext_vector_type(8))) unsigned short u16x8;

__device__ __forceinline__ unsigned short f2bf(float f) {
  __hip_bfloat16 h = __float2bfloat16(f);
  return *reinterpret_cast<unsigned short*>(&h);
}

__device__ __forceinline__ void lds_load16(const void* g, void* l) {
  __builtin_amdgcn_global_load_lds((__attribute__((address_space(1))) void*)g,
                                   (__attribute__((address_space(3))) void*)l,
                                   16, 0, 0);
}

// swizzled LDS fragment read: tile layout [rows][64 bf16] (128B rows, 8x16B
// chunks); content chunk cc of row lives at physical chunk cc ^ (row&7)
__device__ __forceinline__ const bf16x8* lds_frag(const char* base, int row,
                                                  int cc) {
  return (const bf16x8*)(base + row * 128 + ((cc ^ (row & 7)) << 4));
}

// bijective XCD swizzle (nwg % 8 == 0): each XCD owns a contiguous logical chunk
__device__ __forceinline__ int xcd_swz(int bid, int nwg) {
  return (bid & 7) * (nwg >> 3) + (bid >> 3);
}

// map flat row-block g -> (expert e, local row-block mb); rowbase is 256*g
__device__ __forceinline__ bool rb_lookup(const int* counts, int g, int* e_out,
                                          int* mb_out, int* cnt_out) {
  int acc = 0;
#pragma unroll
  for (int i = 0; i < NE; ++i) {
    int c = counts[i];
    int rb = (c + 255) >> 8;
    if (g < acc + rb) {
      *e_out = i;
      *mb_out = g - acc;
      *cnt_out = c;
      return true;
    }
    acc += rb;
  }
  return false;
}

// ---------------- router: 1 wave per token ----------------
__global__ void router_kernel(const float* __restrict__ x,
                              const float* __restrict__ rw,
                              int* __restrict__ counts,
                              int* __restrict__ perm,
                              int* __restrict__ se,
                              float* __restrict__ wtok) {
  const int t = blockIdx.x;
  const int lane = threadIdx.x;  // 64 threads
  float acc[NE];
#pragma unroll
  for (int e = 0; e < NE; ++e) acc[e] = 0.f;
  const float* xr = x + (size_t)t * H_DIM;
#pragma unroll
  for (int it = 0; it < H_DIM / 64; ++it) {
    int d = it * 64 + lane;
    float xv = xr[d];
#pragma unroll
    for (int e = 0; e < NE; ++e) acc[e] += xv * rw[e * H_DIM + d];
  }
#pragma unroll
  for (int e = 0; e < NE; ++e) {
#pragma unroll
    for (int off = 32; off > 0; off >>= 1) acc[e] += __shfl_xor(acc[e], off);
  }
  if (lane == 0) {
    int i0 = 0;
#pragma unroll
    for (int e = 1; e < NE; ++e)
      if (acc[e] > acc[i0]) i0 = e;
    int i1 = (i0 == 0) ? 1 : 0;
#pragma unroll
    for (int e = 0; e < NE; ++e)
      if (e != i0 && acc[e] > acc[i1]) i1 = e;
    float la = acc[i0], lb = acc[i1];
    float r = expf(lb - la);          // <= 1
    float wa = 1.f / (1.f + r);       // normalized top-2 softmax weights
    float wb = 1.f - wa;
    int p0 = atomicAdd(&counts[i0], 1);
    perm[i0 * CAP + p0] = t;
    se[2 * t + 0] = (i0 << 20) | p0;
    wtok[2 * t + 0] = wa;
    int p1 = atomicAdd(&counts[i1], 1);
    perm[i1 * CAP + p1] = t;
    se[2 * t + 1] = (i1 << 20) | p1;
    wtok[2 * t + 1] = wb;
  }
}

// ---------------- x -> bf16 ----------------
__global__ void convert_x_kernel(const float* __restrict__ x,
                                 unsigned short* __restrict__ xb) {
  int i = blockIdx.x * blockDim.x + threadIdx.x;  // one float4 each
  float4 v = reinterpret_cast<const float4*>(x)[i];
  ushort4 o;
  o.x = f2bf(v.x); o.y = f2bf(v.y); o.z = f2bf(v.z); o.w = f2bf(v.w);
  reinterpret_cast<ushort4*>(xb)[i] = o;
}

// ---------------- transpose + convert: src [E][R][C] f32 -> dst [E][C][R] bf16
__global__ void __launch_bounds__(256) transpose_conv_kernel(
    const float* __restrict__ src, unsigned short* __restrict__ dst,
    int R, int C) {
  __shared__ float tile[64][65];
  const int e = blockIdx.z;
  const int c0 = blockIdx.x * 64, r0 = blockIdx.y * 64;
  const float* s = src + (size_t)e * R * C;
  unsigned short* d = dst + (size_t)e * R * C;
  const int tid = threadIdx.x;
  const int lr = tid >> 4, lc = (tid & 15) << 2;
#pragma unroll
  for (int j = 0; j < 4; ++j) {
    float4 v = *reinterpret_cast<const float4*>(
        &s[(size_t)(r0 + j * 16 + lr) * C + c0 + lc]);
    tile[j * 16 + lr][lc + 0] = v.x;
    tile[j * 16 + lr][lc + 1] = v.y;
    tile[j * 16 + lr][lc + 2] = v.z;
    tile[j * 16 + lr][lc + 3] = v.w;
  }
  __syncthreads();
  const int oc = tid >> 3, orr = (tid & 7) << 3;
#pragma unroll
  for (int j = 0; j < 2; ++j) {
    int c = j * 32 + oc;
    u16x8 o;
#pragma unroll
    for (int k = 0; k < 8; ++k) o[k] = f2bf(tile[orr + k][c]);
    *reinterpret_cast<u16x8*>(&d[(size_t)(c0 + c) * R + r0 + orr]) = o;
  }
}

// ---------------- FFN1: inter = gelu(X[perm] @ w_in + b_in), bf16 out --------
// 256x256 tile, BK=64, 512 thr (8 waves 2Mx4N). T3-min single-barrier dbuf
// (stage(next) issued before compute), T2 chunk-swizzle, T5 setprio.
// Compact dispatch: grid = 16nb * RBMAX(g), rowbase = 256*g. LDS 128KB.
// LDS-staged coalesced epilogue (16B/lane).
__global__ void __launch_bounds__(512, 2) ffn1_kernel(
    const unsigned short* __restrict__ xb,
    const unsigned short* __restrict__ win_t,  // [E][I][H]
    const float* __restrict__ b_in,            // [E][I]
    const int* __restrict__ counts,
    const int* __restrict__ perm,
    unsigned short* __restrict__ inter) {
  const int logical = xcd_swz(blockIdx.x, 16 * RBMAX);
  const int nb = logical / RBMAX;  // 0..15, consecutive logicals share panel
  const int g = logical % RBMAX;
  int e, mb, cnt;
  if (!rb_lookup(counts, g, &e, &mb, &cnt)) return;

  extern __shared__ char smem[];  // [2][ A 32KB | B 32KB ]

  const int tid = threadIdx.x;
  int tokr[4];
#pragma unroll
  for (int it = 0; it < 4; ++it) {
    int r = (it * 512 + tid) >> 3;
    tokr[it] = perm[e * CAP + min(mb * 256 + r, cnt - 1)];
  }

  const int wave = tid >> 6, lane = tid & 63;
  const int wr = wave >> 2, wn = wave & 3;  // 2M x 4N
  const int l16 = lane & 15, l4 = lane >> 4;
  const unsigned short* Bbase =
      win_t + (size_t)e * I_DIM * H_DIM + (size_t)(nb * 256) * H_DIM;

  // stage tile kt into buffer b: source chunk pre-swizzled (T2 both-sides)
  auto stage = [&](int b, int kt) {
#pragma unroll
    for (int it = 0; it < 4; ++it) {
      int id = it * 512 + tid;
      int r = id >> 3;
      int cs = (id & 7) ^ (r & 7);
      lds_load16(xb + (size_t)tokr[it] * H_DIM + kt * 64 + cs * 8,
                 smem + b * 65536 + id * 16);
      lds_load16(Bbase + (size_t)r * H_DIM + kt * 64 + cs * 8,
                 smem + b * 65536 + 32768 + id * 16);
    }
  };

  f32x4 acc[8][4] = {};

  stage(0, 0);
  __syncthreads();  // tile 0 resident

  const int NK = H_DIM / 64;  // 16
  for (int kt = 0; kt < NK; ++kt) {
    const int cur = kt & 1;
    if (kt + 1 < NK) stage(cur ^ 1, kt + 1);  // issue first; hides under MFMA
    const char* Ab = smem + cur * 65536;
    const char* Bb = Ab + 32768;
#pragma unroll
    for (int kk = 0; kk < 2; ++kk) {
      bf16x8 af[8], bv[4];
#pragma unroll
      for (int m = 0; m < 8; ++m)
        af[m] = *lds_frag(Ab, wr * 128 + m * 16 + l16, kk * 4 + l4);
#pragma unroll
      for (int n = 0; n < 4; ++n)
        bv[n] = *lds_frag(Bb, wn * 64 + n * 16 + l16, kk * 4 + l4);
      __builtin_amdgcn_s_setprio(1);
#pragma unroll
      for (int m = 0; m < 8; ++m)
#pragma unroll
        for (int n = 0; n < 4; ++n)
          acc[m][n] =
              __builtin_amdgcn_mfma_f32_16x16x32_bf16(af[m], bv[n], acc[m][n], 0, 0, 0);
      __builtin_amdgcn_s_setprio(0);
    }
    __syncthreads();  // drains stage (vmcnt0) + guards buffer swap
  }

  // ---- epilogue: GELU, then coalesce via per-wave LDS slice (16KB each) ----
  const size_t rowbase = (size_t)g * 256;
  unsigned short* slice = (unsigned short*)(smem + wave * 16384);
#pragma unroll
  for (int n = 0; n < 4; ++n) {
    float bias = b_in[e * I_DIM + nb * 256 + wn * 64 + n * 16 + l16];
#pragma unroll
    for (int m = 0; m < 8; ++m) {
#pragma unroll
      for (int j = 0; j < 4; ++j) {
        float v = acc[m][n][j] + bias;
        // tanh-form GELU: v * sigmoid(1.59577(v + 0.044715 v^3)); |err| <~1e-3
        float t = __expf(-1.5957691216057308f * v - 0.07135481627f * v * v * v);
        float gg = v / (1.f + t);
        slice[(m * 16 + l4 * 4 + j) * 64 + n * 16 + l16] = f2bf(gg);
      }
    }
  }
  // wave-local write->read: compiler inserts lgkmcnt; no barrier needed
#pragma unroll
  for (int it = 0; it < 16; ++it) {
    int row = it * 8 + (lane >> 3);        // 0..127
    int colb = (lane & 7) * 8;             // 8 bf16 = 16B
    u16x8 v = *(const u16x8*)&slice[row * 64 + colb];
    *(u16x8*)&inter[(rowbase + wr * 128 + row) * (size_t)I_DIM + nb * 256 +
                    wn * 64 + colb] = v;
  }
}

// ---------------- FFN2: y[slot] = inter @ w_out + b_out (dense, no atomics) --
// 256x128 tile, BK=64, 512 thr (8 waves 4Mx2N). T3-min single-barrier dbuf.
// Compact dispatch: grid = 8nb * RBMAX(g). LDS 96KB. Coalesced f32 epilogue.
__global__ void __launch_bounds__(512, 2) ffn2_kernel(
    const unsigned short* __restrict__ inter,
    const unsigned short* __restrict__ wout_t,  // [E][H][I]
    const float* __restrict__ b_out,            // [E][H]
    const int* __restrict__ counts,
    float* __restrict__ y) {                    // [slot][H]
  const int logical = xcd_swz(blockIdx.x, 8 * RBMAX);
  const int nb = logical / RBMAX;  // 0..7
  const int g = logical % RBMAX;
  int e, mb, cnt;
  if (!rb_lookup(counts, g, &e, &mb, &cnt)) return;
  (void)mb;

  extern __shared__ char smem[];  // [2][ A 32KB | B 16KB ]

  const int tid = threadIdx.x;
  const int wave = tid >> 6, lane = tid & 63;
  const int wrm = wave >> 1, wn2 = wave & 1;  // 4M x 2N
  const int l16 = lane & 15, l4 = lane >> 4;
  const unsigned short* Bbase =
      wout_t + (size_t)e * H_DIM * I_DIM + (size_t)(nb * 128) * I_DIM;
  const size_t rowbase = (size_t)g * 256;

  auto stage = [&](int b, int kt) {
#pragma unroll
    for (int it = 0; it < 4; ++it) {
      int id = it * 512 + tid;
      int r = id >> 3;
      int cs = (id & 7) ^ (r & 7);
      lds_load16(inter + (rowbase + r) * (size_t)I_DIM + kt * 64 + cs * 8,
                 smem + b * 49152 + id * 16);
    }
#pragma unroll
    for (int it = 0; it < 2; ++it) {
      int id = it * 512 + tid;
      int r = id >> 3;
      int cs = (id & 7) ^ (r & 7);
      lds_load16(Bbase + (size_t)r * I_DIM + kt * 64 + cs * 8,
                 smem + b * 49152 + 32768 + id * 16);
    }
  };

  f32x4 acc[4][4] = {};

  stage(0, 0);
  __syncthreads();

  const int NK = I_DIM / 64;  // 64
  for (int kt = 0; kt < NK; ++kt) {
    const int cur = kt & 1;
    if (kt + 1 < NK) stage(cur ^ 1, kt + 1);
    const char* Ab = smem + cur * 49152;
    const char* Bb = Ab + 32768;
#pragma unroll
    for (int kk = 0; kk < 2; ++kk) {
      bf16x8 af[4], bv[4];
#pragma unroll
      for (int m = 0; m < 4; ++m)
        af[m] = *lds_frag(Ab, wrm * 64 + m * 16 + l16, kk * 4 + l4);
#pragma unroll
      for (int n = 0; n < 4; ++n)
        bv[n] = *lds_frag(Bb, wn2 * 64 + n * 16 + l16, kk * 4 + l4);
      __builtin_amdgcn_s_setprio(1);
#pragma unroll
      for (int m = 0; m < 4; ++m)
#pragma unroll
        for (int n = 0; n < 4; ++n)
          acc[m][n] =
              __builtin_amdgcn_mfma_f32_16x16x32_bf16(af[m], bv[n], acc[m][n], 0, 0, 0);
      __builtin_amdgcn_s_setprio(0);
    }
    __syncthreads();
  }

  // ---- epilogue: two 32-row passes through per-wave 8KB LDS slice ----
  float* slice = (float*)(smem + wave * 8192);
  float bias[4];
#pragma unroll
  for (int n = 0; n < 4; ++n)
    bias[n] = b_out[e * H_DIM + nb * 128 + wn2 * 64 + n * 16 + l16];
#pragma unroll
  for (int p = 0; p < 2; ++p) {
#pragma unroll
    for (int mm = 0; mm < 2; ++mm) {
      int m = p * 2 + mm;
#pragma unroll
      for (int n = 0; n < 4; ++n) {
#pragma unroll
        for (int j = 0; j < 4; ++j) {
          slice[(mm * 16 + l4 * 4 + j) * 64 + n * 16 + l16] =
              acc[m][n][j] + bias[n];
        }
      }
    }
    // wave-local readback: 32 rows x 256B, 16B/lane
#pragma unroll
    for (int it = 0; it < 8; ++it) {
      int row = it * 4 + (lane >> 4);      // 0..31
      int col = (lane & 15) * 4;           // 4 floats = 16B
      float4 v = *(const float4*)&slice[row * 64 + col];
      *(float4*)&y[(rowbase + wrm * 64 + p * 32 + row) * (size_t)H_DIM +
                   nb * 128 + wn2 * 64 + col] = v;
    }
  }
}

// ---------------- combine: out[t] = w0*y[slot0] + w1*y[slot1] ---------------
__global__ void __launch_bounds__(256) combine_kernel(
    const float* __restrict__ y, const int* __restrict__ counts,
    const int* __restrict__ se, const float* __restrict__ wtok,
    float* __restrict__ out) {
  const int t = blockIdx.x;
  int poff[NE];
  int run = 0;
#pragma unroll
  for (int e = 0; e < NE; ++e) {
    poff[e] = run;
    run += (counts[e] + 255) & ~255;
  }
  int c0 = se[2 * t], c1 = se[2 * t + 1];
  float w0 = wtok[2 * t], w1 = wtok[2 * t + 1];
  const float* y0 = y + (size_t)(poff[c0 >> 20] + (c0 & 0xFFFFF)) * H_DIM;
  const float* y1 = y + (size_t)(poff[c1 >> 20] + (c1 & 0xFFFFF)) * H_DIM;
  int h = threadIdx.x * 4;
  float4 a = *reinterpret_cast<const float4*>(y0 + h);
  float4 b = *reinterpret_cast<const float4*>(y1 + h);
  float4 o;
  o.x = w0 * a.x + w1 * b.x;
  o.y = w0 * a.y + w1 * b.y;
  o.z = w0 * a.z + w1 * b.z;
  o.w = w0 * a.w + w1 * b.w;
  *reinterpret_cast<float4*>(out + (size_t)t * H_DIM + h) = o;
}

extern "C" void kernel_launch(void* const* d_in, const int* in_sizes, int n_in,
                              void* d_out, int out_size, void* d_ws, size_t ws_size,
                              hipStream_t stream) {
  const float* x     = (const float*)d_in[0];
  const float* rw    = (const float*)d_in[1];
  const float* w_in  = (const float*)d_in[2];
  const float* b_in  = (const float*)d_in[3];
  const float* w_out = (const float*)d_in[4];
  const float* b_out = (const float*)d_in[5];
  float* out = (float*)d_out;

  char* ws = (char*)d_ws;
  size_t off = 0;
  auto alloc = [&](size_t bytes) {
    char* p = ws + off;
    off = (off + bytes + 255) & ~(size_t)255;
    return p;
  };
  int* counts            = (int*)alloc(NE * 4);
  int* perm              = (int*)alloc((size_t)NE * CAP * 4);
  int* se                = (int*)alloc((size_t)T_TOK * 2 * 4);
  float* wtok            = (float*)alloc((size_t)T_TOK * 2 * 4);
  unsigned short* xb     = (unsigned short*)alloc((size_t)T_TOK * H_DIM * 2);
  unsigned short* win_t  = (unsigned short*)alloc((size_t)NE * H_DIM * I_DIM * 2);
  unsigned short* wout_t = (unsigned short*)alloc((size_t)NE * H_DIM * I_DIM * 2);
  unsigned short* inter  = (unsigned short*)alloc((size_t)(T_TOK * 2 + NE * 256) * I_DIM * 2);
  // y overlays the dead xb+win_t region (both dead before ffn2 writes y):
  // need 10240*1024*4 = 42MB <= 8.4MB + 64MB
  float* y = (float*)xb;
  if (off > ws_size) return;  // ws too small -> visible correctness failure

  hipMemsetAsync(counts, 0, NE * sizeof(int), stream);

  static bool attr_done = false;
  if (!attr_done) {
    hipFuncSetAttribute((const void*)ffn1_kernel,
                        hipFuncAttributeMaxDynamicSharedMemorySize, 131072);
    hipFuncSetAttribute((const void*)ffn2_kernel,
                        hipFuncAttributeMaxDynamicSharedMemorySize, 98304);
    attr_done = true;
  }

  router_kernel<<<T_TOK, 64, 0, stream>>>(x, rw, counts, perm, se, wtok);
  convert_x_kernel<<<(T_TOK * H_DIM / 4) / 256, 256, 0, stream>>>(x, xb);
  transpose_conv_kernel<<<dim3(I_DIM / 64, H_DIM / 64, NE), 256, 0, stream>>>(
      w_in, win_t, H_DIM, I_DIM);
  transpose_conv_kernel<<<dim3(H_DIM / 64, I_DIM / 64, NE), 256, 0, stream>>>(
      w_out, wout_t, I_DIM, H_DIM);
  ffn1_kernel<<<16 * RBMAX, 512, 131072, stream>>>(xb, win_t, b_in, counts,
                                                   perm, inter);
  ffn2_kernel<<<8 * RBMAX, 512, 98304, stream>>>(inter, wout_t, b_out, counts, y);
  combine_kernel<<<T_TOK, 256, 0, stream>>>(y, counts, se, wtok, out);
}